// Round 7
// baseline (550.370 us; speedup 1.0000x reference)
//
#include <hip/hip_runtime.h>
#include <hip/hip_fp16.h>

#define NU 50000
#define NP 50000
#define NN 100000
#define NE 600000
#define H  128
#define O  16

typedef __attribute__((ext_vector_type(8))) _Float16 half8;
typedef __attribute__((ext_vector_type(4))) _Float16 h4v;
typedef __attribute__((ext_vector_type(4))) float f32x4;

// ---------------------------------------------------------------- fused weight prep + cnt zero + epack pad
__global__ void k_prep(const float* __restrict__ Wu, const float* __restrict__ Wp,
                       const float* __restrict__ W1, const float* __restrict__ W2,
                       const float* __restrict__ W3, const float* __restrict__ Wo,
                       __half* __restrict__ whU, __half* __restrict__ wlU,
                       __half* __restrict__ whP, __half* __restrict__ wlP,
                       __half* __restrict__ wh1, __half* __restrict__ wl1,
                       __half* __restrict__ wh2, __half* __restrict__ wl2,
                       __half* __restrict__ wh3, __half* __restrict__ wl3,
                       __half* __restrict__ whO, __half* __restrict__ wlO,
                       int* __restrict__ cnt, int2* __restrict__ epack) {
    int idx = blockIdx.x * blockDim.x + threadIdx.x;
    if (idx >= 75776) {
        int i = idx - 75776;
        if (i < NN) cnt[i] = 0;
        else if (i < NN + 8) { int2 z; z.x = 0; z.y = 0; epack[NE + (i - NN)] = z; }
        return;
    }
    const float* W; __half *Wh, *Wl; int K, KPAD, NC;
    if      (idx <  8192) {              W = Wu; Wh = whU; Wl = wlU; K =  64; KPAD =  64; NC = 128; }
    else if (idx < 24576) { idx -=  8192; W = Wp; Wh = whP; Wl = wlP; K = 100; KPAD = 128; NC = 128; }
    else if (idx < 40960) { idx -= 24576; W = W1; Wh = wh1; Wl = wl1; K = 128; KPAD = 128; NC = 128; }
    else if (idx < 57344) { idx -= 40960; W = W2; Wh = wh2; Wl = wl2; K = 128; KPAD = 128; NC = 128; }
    else if (idx < 73728) { idx -= 57344; W = W3; Wh = wh3; Wl = wl3; K = 128; KPAD = 128; NC = 128; }
    else                  { idx -= 73728; W = Wo; Wh = whO; Wl = wlO; K = 128; KPAD = 128; NC =  16; }
    int n = idx / KPAD, k = idx - n * KPAD;
    float x = (k < K) ? W[k * NC + n] * 16.0f : 0.0f;
    __half h = __float2half_rn(x);
    __half l = __float2half_rn(x - __half2float(h));
    Wh[idx] = h; Wl[idx] = l;
}

// ---------------------------------------------------------------- degree count + rank
__global__ void k_count(const int* __restrict__ dst, int* __restrict__ cnt,
                        int* __restrict__ rank, int E) {
    int e = blockIdx.x * blockDim.x + threadIdx.x;
    if (e < E) rank[e] = atomicAdd(&cnt[dst[e]], 1);
}

// ---------------------------------------------------------------- exclusive scan
#define SCAN_TPB 256
#define SCAN_VPT 4
#define SCAN_CHUNK (SCAN_TPB * SCAN_VPT)   // 1024 -> consumers use >>10

__global__ void k_scan1(const int* __restrict__ in, int* __restrict__ out,
                        int* __restrict__ bsums, float* __restrict__ dinv, int n) {
    __shared__ int sh[SCAN_TPB];
    int t = threadIdx.x, b = blockIdx.x;
    int base = b * SCAN_CHUNK + t * SCAN_VPT;
    int v[SCAN_VPT]; int s = 0;
#pragma unroll
    for (int i = 0; i < SCAN_VPT; i++) {
        int idx = base + i;
        v[i] = (idx < n) ? in[idx] : 0;
        if (idx < n) dinv[idx] = rsqrtf((float)(v[i] + 1));
        s += v[i];
    }
    sh[t] = s; __syncthreads();
    for (int off = 1; off < SCAN_TPB; off <<= 1) {
        int x = (t >= off) ? sh[t - off] : 0;
        __syncthreads();
        sh[t] += x;
        __syncthreads();
    }
    int run = (t > 0) ? sh[t - 1] : 0;
    if (t == SCAN_TPB - 1) bsums[b] = sh[t];
#pragma unroll
    for (int i = 0; i < SCAN_VPT; i++) {
        int idx = base + i;
        if (idx < n) out[idx] = run;
        run += v[i];
    }
}

__global__ void k_scan2(int* __restrict__ bsums, int nb) {
    __shared__ int sh[128];
    int t = threadIdx.x;
    int v = (t < nb) ? bsums[t] : 0;
    sh[t] = v; __syncthreads();
    for (int off = 1; off < 128; off <<= 1) {
        int x = (t >= off) ? sh[t - off] : 0;
        __syncthreads();
        sh[t] += x;
        __syncthreads();
    }
    if (t < nb) bsums[t] = sh[t] - v;
}

// ---------------------------------------------------------------- CSR fill (atomic-free)
__global__ void k_fill(const int* __restrict__ src, const int* __restrict__ dst,
                       const int* __restrict__ offs, const int* __restrict__ bsums,
                       const int* __restrict__ rank, const float* __restrict__ dinv,
                       int2* __restrict__ epack, int E) {
    int e = blockIdx.x * blockDim.x + threadIdx.x;
    if (e < E) {
        int s = src[e], d = dst[e];
        int p = offs[d] + bsums[d >> 10] + rank[e];
        int2 r;
        r.x = s;
        r.y = __float_as_int(dinv[s] * dinv[d]);
        epack[p] = r;
    }
}

// ---------------------------------------------------------------- register-resident MFMA GEMM
// (unchanged from R6 measured config: W frags register-resident, NI node chains)
template <typename AT, int K, int KPAD, int NI, int MI, int NOUT, bool BIAS, bool F32OUT>
__device__ __forceinline__
void gemm_body(const AT* __restrict__ X,
               const __half* __restrict__ Wh, const __half* __restrict__ Wl,
               const float* __restrict__ bias, void* __restrict__ Cout,
               int M, int orow0, int vb) {
    constexpr int KS = KPAD / 32;
    constexpr int CSPLIT = NOUT / (16 * MI);
    const int tid  = threadIdx.x;
    const int wid  = tid >> 6, lane = tid & 63;
    const int lm   = lane & 15, q = lane >> 4;
    const int gw   = vb * 4 + wid;
    const int tile = gw / CSPLIT;
    const int c0   = (gw % CSPLIT) * (MI * 16);
    const int NT   = (M + NI * 16 - 1) / (NI * 16);
    if (tile >= NT) return;
    const int n0 = tile * (NI * 16);

    half8 wh[MI][KS], wl[MI][KS];
#pragma unroll
    for (int mi = 0; mi < MI; mi++)
#pragma unroll
        for (int ks = 0; ks < KS; ks++) {
            const size_t b = (size_t)(c0 + mi * 16 + lm) * KPAD + ks * 32 + q * 8;
            wh[mi][ks] = *(const half8*)&Wh[b];
            wl[mi][ks] = *(const half8*)&Wl[b];
        }

    f32x4 acc[NI][MI];
#pragma unroll
    for (int ni = 0; ni < NI; ni++)
#pragma unroll
        for (int mi = 0; mi < MI; mi++) acc[ni][mi] = (f32x4)0.0f;

#pragma unroll
    for (int ni = 0; ni < NI; ni++) {
        const int node = n0 + ni * 16 + lm;
        half8 xf[KS];
        if (node < M) {
            if constexpr (sizeof(AT) == 2) {
#pragma unroll
                for (int ks = 0; ks < KS; ks++)
                    xf[ks] = *(const half8*)((const __half*)X + (size_t)node * KPAD + ks * 32 + q * 8);
            } else {
                const float* xp = (const float*)X + (size_t)node * K;
#pragma unroll
                for (int ks = 0; ks < KS; ks++) {
                    const int kb = ks * 32 + q * 8;
                    if (kb + 8 <= K) {
                        float4 v0 = *(const float4*)(xp + kb);
                        float4 v1 = *(const float4*)(xp + kb + 4);
                        xf[ks][0] = (_Float16)v0.x; xf[ks][1] = (_Float16)v0.y;
                        xf[ks][2] = (_Float16)v0.z; xf[ks][3] = (_Float16)v0.w;
                        xf[ks][4] = (_Float16)v1.x; xf[ks][5] = (_Float16)v1.y;
                        xf[ks][6] = (_Float16)v1.z; xf[ks][7] = (_Float16)v1.w;
                    } else if (kb + 4 <= K) {      // K=100 tail: one aligned float4
                        float4 v0 = *(const float4*)(xp + kb);
                        xf[ks][0] = (_Float16)v0.x; xf[ks][1] = (_Float16)v0.y;
                        xf[ks][2] = (_Float16)v0.z; xf[ks][3] = (_Float16)v0.w;
                        xf[ks][4] = (_Float16)0.0f; xf[ks][5] = (_Float16)0.0f;
                        xf[ks][6] = (_Float16)0.0f; xf[ks][7] = (_Float16)0.0f;
                    } else {
#pragma unroll
                        for (int j = 0; j < 8; j++) xf[ks][j] = (_Float16)0.0f;
                    }
                }
            }
        } else {
#pragma unroll
            for (int ks = 0; ks < KS; ks++)
#pragma unroll
                for (int j = 0; j < 8; j++) xf[ks][j] = (_Float16)0.0f;
        }
#pragma unroll
        for (int ks = 0; ks < KS; ks++)
#pragma unroll
            for (int mi = 0; mi < MI; mi++) {
                acc[ni][mi] = __builtin_amdgcn_mfma_f32_16x16x32_f16(wh[mi][ks], xf[ks], acc[ni][mi], 0, 0, 0);
                acc[ni][mi] = __builtin_amdgcn_mfma_f32_16x16x32_f16(wl[mi][ks], xf[ks], acc[ni][mi], 0, 0, 0);
            }
    }

#pragma unroll
    for (int ni = 0; ni < NI; ni++) {
        const int node = n0 + ni * 16 + lm;
        if (node >= M) continue;
#pragma unroll
        for (int mi = 0; mi < MI; mi++) {
            const int cb = c0 + mi * 16 + q * 4;
            float4 bv = BIAS ? *(const float4*)&bias[cb] : make_float4(0.f, 0.f, 0.f, 0.f);
            float v0 = fmaf(acc[ni][mi][0], 0.0625f, bv.x);
            float v1 = fmaf(acc[ni][mi][1], 0.0625f, bv.y);
            float v2 = fmaf(acc[ni][mi][2], 0.0625f, bv.z);
            float v3 = fmaf(acc[ni][mi][3], 0.0625f, bv.w);
            if constexpr (F32OUT) {
                *(float4*)((float*)Cout + (size_t)(orow0 + node) * NOUT + cb) =
                    make_float4(v0, v1, v2, v3);
            } else {
                __half2 h0 = __floats2half2_rn(v0, v1);
                __half2 h1 = __floats2half2_rn(v2, v3);
                uint2 o; o.x = *(unsigned*)&h0; o.y = *(unsigned*)&h1;
                *(uint2*)((__half*)Cout + (size_t)(orow0 + node) * NOUT + cb) = o;
            }
        }
    }
}

template <typename AT, int K, int KPAD, int NI, int MI, int NOUT, bool BIAS, bool F32OUT>
__launch_bounds__(256)
__global__ void k_gemm_reg(const AT* __restrict__ X,
                           const __half* __restrict__ Wh, const __half* __restrict__ Wl,
                           const float* __restrict__ bias, void* __restrict__ Cout,
                           int M, int orow0) {
    gemm_body<AT, K, KPAD, NI, MI, NOUT, BIAS, F32OUT>(X, Wh, Wl, bias, Cout, M, orow0, blockIdx.x);
}

// merged user+prod input transform (one launch, block-range split)
__launch_bounds__(256)
__global__ void k_gemm_inputs(const float* __restrict__ user, const float* __restrict__ prod,
                              const __half* __restrict__ whU, const __half* __restrict__ wlU,
                              const __half* __restrict__ whP, const __half* __restrict__ wlP,
                              const float* __restrict__ bu, const float* __restrict__ bp,
                              void* __restrict__ xA, int blkU) {
    if ((int)blockIdx.x < blkU)
        gemm_body<float,  64,  64, 2, 4, 128, true, false>(user, whU, wlU, bu, xA, NU, 0, blockIdx.x);
    else
        gemm_body<float, 100, 128, 2, 2, 128, true, false>(prod, whP, wlP, bp, xA, NP, NU, blockIdx.x - blkU);
}

// ---------------------------------------------------------------- XCD-sliced CSR gather + bias + ReLU
// Feature dim split into 8 slices of 16 cols (3.2 MB/slice < 4 MiB per-XCD L2).
// slice = blockIdx%8: under round-robin block->XCD dispatch, slice s's gathers
// all land on XCD s -> gather table slice stays L2-RESIDENT (R2 counters: 45%
// L2 hit at 25.6MB table; sliced: ~95% after 3.2MB first-touch warm).
// Wave = 2 nodes (one per 32-lane half) x 8 edge-slots x 4 col-lanes (8B each;
// 4 lanes cover the 32B row-slice). Slot-reduction = 3x shfl_xor (4/8/16).
// Correctness does NOT depend on the XCD mapping - only locality/speed.
__launch_bounds__(256)
__global__ void k_aggregate(const __half* __restrict__ y, const int* __restrict__ offs,
                            const int* __restrict__ bsums, const int2* __restrict__ epack,
                            const float* __restrict__ dinv, const float* __restrict__ bias,
                            __half* __restrict__ out) {
    const int b   = blockIdx.x;
    const int s   = b & 7;                      // slice id (== XCD id under %8 dispatch)
    const int wid = threadIdx.x >> 6;
    const int l   = threadIdx.x & 63;
    const int h   = l >> 5, hl = l & 31;
    const int slot = hl >> 2, cl = hl & 3;

    const int node = ((b >> 3) * 4 + wid) * 2 + h;   // NN = 12500*8 -> exact cover

    int e0 = offs[node] + bsums[node >> 10];
    int e1 = (node + 1 < NN) ? (offs[node + 1] + bsums[(node + 1) >> 10]) : NE;
    const int deg  = e1 - e0;
    const int odeg = __shfl_xor(deg, 32, 64);        // other half's degree
    const int iters = (max(deg, odeg) + 7) >> 3;

    const h4v* y4 = (const h4v*)y;              // row = 32 h4v (8B) units
    const int so4 = s * 4 + cl;                 // h4v offset of this lane's 8B in the row

    // self row + bias + dinv preload (overlaps with first gather)
    h4v sv = y4[(size_t)node * 32 + so4];
    float4 bv = *(const float4*)&bias[s * 16 + cl * 4];
    const float di2 = dinv[node] * dinv[node];

    f32x4 acc = (f32x4)0.f;
    for (int it = 0; it < iters; ++it) {
        const int idx  = e0 + it * 8 + slot;
        const int lidx = min(idx, NE + 7);      // epack padded with 8 zero entries
        int2 p = epack[lidx];
        float w = (idx < e1) ? __int_as_float(p.y) : 0.f;
        h4v v = y4[(size_t)p.x * 32 + so4];     // 32B slice of a random row (L2-hit)
        acc[0] = fmaf((float)v[0], w, acc[0]);
        acc[1] = fmaf((float)v[1], w, acc[1]);
        acc[2] = fmaf((float)v[2], w, acc[2]);
        acc[3] = fmaf((float)v[3], w, acc[3]);
    }

    // reduce the 8 edge-slots within each 32-lane half
#pragma unroll
    for (int m = 4; m <= 16; m <<= 1) {
        acc[0] += __shfl_xor(acc[0], m, 64);
        acc[1] += __shfl_xor(acc[1], m, 64);
        acc[2] += __shfl_xor(acc[2], m, 64);
        acc[3] += __shfl_xor(acc[3], m, 64);
    }

    if (slot == 0) {
        float r0 = fmaf((float)sv[0], di2, acc[0]) + bv.x;
        float r1 = fmaf((float)sv[1], di2, acc[1]) + bv.y;
        float r2 = fmaf((float)sv[2], di2, acc[2]) + bv.z;
        float r3 = fmaf((float)sv[3], di2, acc[3]) + bv.w;
        __half2 ha = __floats2half2_rn(fmaxf(r0, 0.f), fmaxf(r1, 0.f));
        __half2 hb = __floats2half2_rn(fmaxf(r2, 0.f), fmaxf(r3, 0.f));
        uint2 o; o.x = *(unsigned*)&ha; o.y = *(unsigned*)&hb;
        *(uint2*)(out + (size_t)node * H + s * 16 + cl * 4) = o;
    }
}

// ---------------------------------------------------------------- launch
extern "C" void kernel_launch(void* const* d_in, const int* in_sizes, int n_in,
                              void* d_out, int out_size, void* d_ws, size_t ws_size,
                              hipStream_t stream) {
    const float* user = (const float*)d_in[0];
    const float* prod = (const float*)d_in[1];
    const int*   eidx = (const int*)  d_in[2];
    const int*   edst = eidx + NE;
    const int*   esrc = eidx;
    const float* Wu = (const float*)d_in[3];
    const float* bu = (const float*)d_in[4];
    const float* Wp = (const float*)d_in[5];
    const float* bp = (const float*)d_in[6];
    const float* W1 = (const float*)d_in[7];
    const float* b1 = (const float*)d_in[8];
    const float* W2 = (const float*)d_in[9];
    const float* b2 = (const float*)d_in[10];
    const float* W3 = (const float*)d_in[11];
    const float* b3 = (const float*)d_in[12];
    const float* Wo = (const float*)d_in[13];
    const float* bo = (const float*)d_in[14];
    float* out = (float*)d_out;

    char* ws = (char*)d_ws;
    size_t p = 0;
    auto alloc = [&](size_t bytes) -> void* {
        void* r = ws + p;
        p += (bytes + 255) & ~(size_t)255;
        return r;
    };
    __half* xA   = (__half*)alloc((size_t)NN * H * 2);
    __half* xB   = (__half*)alloc((size_t)NN * H * 2);
    int*   cnt   = (int*)  alloc((size_t)NN * 4);
    int*   rank  = (int*)  alloc((size_t)NE * 4);
    int*   offs  = (int*)  alloc((size_t)(NN + 1) * 4);
    float* dinv  = (float*)alloc((size_t)NN * 4);
    int2*  epack = (int2*) alloc((size_t)(NE + 8) * 8);
    int*   bsums = (int*)  alloc(128 * 4);
    __half* whU = (__half*)alloc(128 * 64 * 2);
    __half* wlU = (__half*)alloc(128 * 64 * 2);
    __half* whP = (__half*)alloc(128 * 128 * 2);
    __half* wlP = (__half*)alloc(128 * 128 * 2);
    __half* wh1 = (__half*)alloc(128 * 128 * 2);
    __half* wl1 = (__half*)alloc(128 * 128 * 2);
    __half* wh2 = (__half*)alloc(128 * 128 * 2);
    __half* wl2 = (__half*)alloc(128 * 128 * 2);
    __half* wh3 = (__half*)alloc(128 * 128 * 2);
    __half* wl3 = (__half*)alloc(128 * 128 * 2);
    __half* whO = (__half*)alloc(16 * 128 * 2);
    __half* wlO = (__half*)alloc(16 * 128 * 2);

    const int NBLK = (NN + SCAN_CHUNK - 1) / SCAN_CHUNK;   // 98

    // weight prep + cnt zero + epack pad (one launch)
    k_prep<<<(75776 + NN + 8 + 255) / 256, 256, 0, stream>>>(
        Wu, Wp, W1, W2, W3, Wo,
        whU, wlU, whP, wlP, wh1, wl1, wh2, wl2, wh3, wl3, whO, wlO, cnt, epack);

    // graph structure
    k_count<<<(NE + 255) / 256, 256, 0, stream>>>(edst, cnt, rank, NE);
    k_scan1<<<NBLK, SCAN_TPB, 0, stream>>>(cnt, offs, bsums, dinv, NN);
    k_scan2<<<1, 128, 0, stream>>>(bsums, NBLK);
    k_fill <<<(NE + 255) / 256, 256, 0, stream>>>(esrc, edst, offs, bsums, rank, dinv,
                                                  epack, NE);

    // input feature transforms -> xA (fp16), merged into one launch
    {
        constexpr int blkU = (1563 * 2 + 3) / 4;   // 782
        constexpr int blkP = (1563 * 4 + 3) / 4;   // 1563
        k_gemm_inputs<<<blkU + blkP, 256, 0, stream>>>(
            user, prod, whU, wlU, whP, wlP, bu, bp, xA, blkU);
    }

    // hidden gemms: NT=1563, CSPLIT=2 -> 3126 waves -> 782 blocks
    const int blkG = (1563 * 2 + 3) / 4;   // 782
    const int blkO = (1563 + 3) / 4;       // 391

    // aggregate grid: 8 slices x (NN/8 nodes / (4 waves * 2 nodes)) = NN blocks
    const int blkA = NN;                   // 100000 blocks, slice = blk % 8

    // layer 1
    k_gemm_reg<__half, 128, 128, 4, 4, 128, false, false><<<blkG, 256, 0, stream>>>(xA, wh1, wl1, nullptr, xB, NN, 0);
    k_aggregate<<<blkA, 256, 0, stream>>>(xB, offs, bsums, epack, dinv, b1, xA);
    // layer 2
    k_gemm_reg<__half, 128, 128, 4, 4, 128, false, false><<<blkG, 256, 0, stream>>>(xA, wh2, wl2, nullptr, xB, NN, 0);
    k_aggregate<<<blkA, 256, 0, stream>>>(xB, offs, bsums, epack, dinv, b2, xA);
    // layer 3
    k_gemm_reg<__half, 128, 128, 4, 4, 128, false, false><<<blkG, 256, 0, stream>>>(xA, wh3, wl3, nullptr, xB, NN, 0);
    k_aggregate<<<blkA, 256, 0, stream>>>(xB, offs, bsums, epack, dinv, b3, xA);

    // output head [NN,128] @ [128,16] + bo -> fp32 out
    k_gemm_reg<__half, 128, 128, 4, 1, 16, true, true><<<blkO, 256, 0, stream>>>(xA, whO, wlO, bo, out, NN, 0);
}

// Round 8
// 299.757 us; speedup vs baseline: 1.8361x; 1.8361x over previous
//
#include <hip/hip_runtime.h>
#include <hip/hip_fp16.h>

#define NU 50000
#define NP 50000
#define NN 100000
#define NE 600000
#define H  128
#define O  16

typedef __attribute__((ext_vector_type(8))) _Float16 half8;
typedef __attribute__((ext_vector_type(4))) _Float16 h4v;
typedef __attribute__((ext_vector_type(4))) float f32x4;

// ---------------------------------------------------------------- fused prep:
// [0,75776)            : 2-term f16 weight decomposition (x16 scaled)
// [75776, +NN)         : zero cnt
// [+NN, +NN+8)         : zero epack pad entries
// [175784, +NU*16)     : user fp32 -> fp16 row-convert   (xU [NU][64])
// [+NU*16, +NP*32)     : prod fp32 -> fp16 pad-convert   (xP [NP][128], k>=100 zero)
__global__ void k_prep(const float* __restrict__ Wu, const float* __restrict__ Wp,
                       const float* __restrict__ W1, const float* __restrict__ W2,
                       const float* __restrict__ W3, const float* __restrict__ Wo,
                       const float* __restrict__ user, const float* __restrict__ prod,
                       __half* __restrict__ whU, __half* __restrict__ wlU,
                       __half* __restrict__ whP, __half* __restrict__ wlP,
                       __half* __restrict__ wh1, __half* __restrict__ wl1,
                       __half* __restrict__ wh2, __half* __restrict__ wl2,
                       __half* __restrict__ wh3, __half* __restrict__ wl3,
                       __half* __restrict__ whO, __half* __restrict__ wlO,
                       __half* __restrict__ xU, __half* __restrict__ xP,
                       int* __restrict__ cnt, int2* __restrict__ epack) {
    int idx = blockIdx.x * blockDim.x + threadIdx.x;
    if (idx >= 175784) {                       // feature conversion ranges
        int i = idx - 175784;
        if (i < NU * 16) {
            int e = i * 4;
            float4 v = *(const float4*)(user + e);
            __half2 a = __floats2half2_rn(v.x, v.y);
            __half2 b = __floats2half2_rn(v.z, v.w);
            uint2 o; o.x = *(unsigned*)&a; o.y = *(unsigned*)&b;
            *(uint2*)(xU + e) = o;
        } else {
            int q = i - NU * 16;
            if (q >= NP * 32) return;
            int row = q >> 5, kq = (q & 31) * 4;
            float4 v;
            if (kq < 100) v = *(const float4*)(prod + row * 100 + kq);  // kq<=96: reads 96..99 ok
            else { v.x = 0.f; v.y = 0.f; v.z = 0.f; v.w = 0.f; }
            __half2 a = __floats2half2_rn(v.x, v.y);
            __half2 b = __floats2half2_rn(v.z, v.w);
            uint2 o; o.x = *(unsigned*)&a; o.y = *(unsigned*)&b;
            *(uint2*)(xP + (size_t)row * 128 + kq) = o;
        }
        return;
    }
    if (idx >= 75776) {
        int i = idx - 75776;
        if (i < NN) cnt[i] = 0;
        else if (i < NN + 8) { int2 z; z.x = 0; z.y = 0; epack[NE + (i - NN)] = z; }
        return;
    }
    const float* W; __half *Wh, *Wl; int K, KPAD, NC;
    if      (idx <  8192) {              W = Wu; Wh = whU; Wl = wlU; K =  64; KPAD =  64; NC = 128; }
    else if (idx < 24576) { idx -=  8192; W = Wp; Wh = whP; Wl = wlP; K = 100; KPAD = 128; NC = 128; }
    else if (idx < 40960) { idx -= 24576; W = W1; Wh = wh1; Wl = wl1; K = 128; KPAD = 128; NC = 128; }
    else if (idx < 57344) { idx -= 40960; W = W2; Wh = wh2; Wl = wl2; K = 128; KPAD = 128; NC = 128; }
    else if (idx < 73728) { idx -= 57344; W = W3; Wh = wh3; Wl = wl3; K = 128; KPAD = 128; NC = 128; }
    else                  { idx -= 73728; W = Wo; Wh = whO; Wl = wlO; K = 128; KPAD = 128; NC =  16; }
    int n = idx / KPAD, k = idx - n * KPAD;
    float x = (k < K) ? W[k * NC + n] * 16.0f : 0.0f;
    __half h = __float2half_rn(x);
    __half l = __float2half_rn(x - __half2float(h));
    Wh[idx] = h; Wl[idx] = l;
}

// ---------------------------------------------------------------- degree count + rank
__global__ void k_count(const int* __restrict__ dst, int* __restrict__ cnt,
                        int* __restrict__ rank, int E) {
    int e = blockIdx.x * blockDim.x + threadIdx.x;
    if (e < E) rank[e] = atomicAdd(&cnt[dst[e]], 1);
}

// ---------------------------------------------------------------- exclusive scan
#define SCAN_TPB 256
#define SCAN_VPT 4
#define SCAN_CHUNK (SCAN_TPB * SCAN_VPT)   // 1024 -> consumers use >>10

__global__ void k_scan1(const int* __restrict__ in, int* __restrict__ out,
                        int* __restrict__ bsums, float* __restrict__ dinv, int n) {
    __shared__ int sh[SCAN_TPB];
    int t = threadIdx.x, b = blockIdx.x;
    int base = b * SCAN_CHUNK + t * SCAN_VPT;
    int v[SCAN_VPT]; int s = 0;
#pragma unroll
    for (int i = 0; i < SCAN_VPT; i++) {
        int idx = base + i;
        v[i] = (idx < n) ? in[idx] : 0;
        if (idx < n) dinv[idx] = rsqrtf((float)(v[i] + 1));
        s += v[i];
    }
    sh[t] = s; __syncthreads();
    for (int off = 1; off < SCAN_TPB; off <<= 1) {
        int x = (t >= off) ? sh[t - off] : 0;
        __syncthreads();
        sh[t] += x;
        __syncthreads();
    }
    int run = (t > 0) ? sh[t - 1] : 0;
    if (t == SCAN_TPB - 1) bsums[b] = sh[t];
#pragma unroll
    for (int i = 0; i < SCAN_VPT; i++) {
        int idx = base + i;
        if (idx < n) out[idx] = run;
        run += v[i];
    }
}

__global__ void k_scan2(int* __restrict__ bsums, int nb) {
    __shared__ int sh[128];
    int t = threadIdx.x;
    int v = (t < nb) ? bsums[t] : 0;
    sh[t] = v; __syncthreads();
    for (int off = 1; off < 128; off <<= 1) {
        int x = (t >= off) ? sh[t - off] : 0;
        __syncthreads();
        sh[t] += x;
        __syncthreads();
    }
    if (t < nb) bsums[t] = sh[t] - v;
}

// ---------------------------------------------------------------- CSR fill (atomic-free)
__global__ void k_fill(const int* __restrict__ src, const int* __restrict__ dst,
                       const int* __restrict__ offs, const int* __restrict__ bsums,
                       const int* __restrict__ rank, const float* __restrict__ dinv,
                       int2* __restrict__ epack, int E) {
    int e = blockIdx.x * blockDim.x + threadIdx.x;
    if (e < E) {
        int s = src[e], d = dst[e];
        int p = offs[d] + bsums[d >> 10] + rank[e];
        int2 r;
        r.x = s;
        r.y = __float_as_int(dinv[s] * dinv[d]);
        epack[p] = r;
    }
}

// ---------------------------------------------------------------- register-resident MFMA GEMM
// (R6 measured config: W frags register-resident, NI node chains)
template <typename AT, int K, int KPAD, int NI, int MI, int NOUT, bool BIAS, bool F32OUT>
__device__ __forceinline__
void gemm_body(const AT* __restrict__ X,
               const __half* __restrict__ Wh, const __half* __restrict__ Wl,
               const float* __restrict__ bias, void* __restrict__ Cout,
               int M, int orow0, int vb) {
    constexpr int KS = KPAD / 32;
    constexpr int CSPLIT = NOUT / (16 * MI);
    const int tid  = threadIdx.x;
    const int wid  = tid >> 6, lane = tid & 63;
    const int lm   = lane & 15, q = lane >> 4;
    const int gw   = vb * 4 + wid;
    const int tile = gw / CSPLIT;
    const int c0   = (gw % CSPLIT) * (MI * 16);
    const int NT   = (M + NI * 16 - 1) / (NI * 16);
    if (tile >= NT) return;
    const int n0 = tile * (NI * 16);

    half8 wh[MI][KS], wl[MI][KS];
#pragma unroll
    for (int mi = 0; mi < MI; mi++)
#pragma unroll
        for (int ks = 0; ks < KS; ks++) {
            const size_t b = (size_t)(c0 + mi * 16 + lm) * KPAD + ks * 32 + q * 8;
            wh[mi][ks] = *(const half8*)&Wh[b];
            wl[mi][ks] = *(const half8*)&Wl[b];
        }

    f32x4 acc[NI][MI];
#pragma unroll
    for (int ni = 0; ni < NI; ni++)
#pragma unroll
        for (int mi = 0; mi < MI; mi++) acc[ni][mi] = (f32x4)0.0f;

#pragma unroll
    for (int ni = 0; ni < NI; ni++) {
        const int node = n0 + ni * 16 + lm;
        half8 xf[KS];
        if (node < M) {
#pragma unroll
            for (int ks = 0; ks < KS; ks++)
                xf[ks] = *(const half8*)((const __half*)X + (size_t)node * KPAD + ks * 32 + q * 8);
        } else {
#pragma unroll
            for (int ks = 0; ks < KS; ks++)
#pragma unroll
                for (int j = 0; j < 8; j++) xf[ks][j] = (_Float16)0.0f;
        }
#pragma unroll
        for (int ks = 0; ks < KS; ks++)
#pragma unroll
            for (int mi = 0; mi < MI; mi++) {
                acc[ni][mi] = __builtin_amdgcn_mfma_f32_16x16x32_f16(wh[mi][ks], xf[ks], acc[ni][mi], 0, 0, 0);
                acc[ni][mi] = __builtin_amdgcn_mfma_f32_16x16x32_f16(wl[mi][ks], xf[ks], acc[ni][mi], 0, 0, 0);
            }
    }

#pragma unroll
    for (int ni = 0; ni < NI; ni++) {
        const int node = n0 + ni * 16 + lm;
        if (node >= M) continue;
#pragma unroll
        for (int mi = 0; mi < MI; mi++) {
            const int cb = c0 + mi * 16 + q * 4;
            float4 bv = BIAS ? *(const float4*)&bias[cb] : make_float4(0.f, 0.f, 0.f, 0.f);
            float v0 = fmaf(acc[ni][mi][0], 0.0625f, bv.x);
            float v1 = fmaf(acc[ni][mi][1], 0.0625f, bv.y);
            float v2 = fmaf(acc[ni][mi][2], 0.0625f, bv.z);
            float v3 = fmaf(acc[ni][mi][3], 0.0625f, bv.w);
            if constexpr (F32OUT) {
                *(float4*)((float*)Cout + (size_t)(orow0 + node) * NOUT + cb) =
                    make_float4(v0, v1, v2, v3);
            } else {
                __half2 h0 = __floats2half2_rn(v0, v1);
                __half2 h1 = __floats2half2_rn(v2, v3);
                uint2 o; o.x = *(unsigned*)&h0; o.y = *(unsigned*)&h1;
                *(uint2*)((__half*)Cout + (size_t)(orow0 + node) * NOUT + cb) = o;
            }
        }
    }
}

template <typename AT, int K, int KPAD, int NI, int MI, int NOUT, bool BIAS, bool F32OUT>
__launch_bounds__(256)
__global__ void k_gemm_reg(const AT* __restrict__ X,
                           const __half* __restrict__ Wh, const __half* __restrict__ Wl,
                           const float* __restrict__ bias, void* __restrict__ Cout,
                           int M, int orow0) {
    gemm_body<AT, K, KPAD, NI, MI, NOUT, BIAS, F32OUT>(X, Wh, Wl, bias, Cout, M, orow0, blockIdx.x);
}

// merged user+prod input transform (one launch, block-range split)
// inputs pre-converted to fp16 by k_prep -> proven half8 fast path, half the bytes
__launch_bounds__(256)
__global__ void k_gemm_inputs(const __half* __restrict__ xU, const __half* __restrict__ xP,
                              const __half* __restrict__ whU, const __half* __restrict__ wlU,
                              const __half* __restrict__ whP, const __half* __restrict__ wlP,
                              const float* __restrict__ bu, const float* __restrict__ bp,
                              void* __restrict__ xA, int blkU) {
    if ((int)blockIdx.x < blkU)
        gemm_body<__half,  64,  64, 2, 4, 128, true, false>(xU, whU, wlU, bu, xA, NU, 0, blockIdx.x);
    else
        gemm_body<__half, 128, 128, 2, 2, 128, true, false>(xP, whP, wlP, bp, xA, NP, NU, blockIdx.x - blkU);
}

// ---------------------------------------------------------------- CSR gather + bias + ReLU
// (R6-measured version, reverted verbatim. R7 post-mortem: 32B row-slice
// gathers tripled FETCH_SIZE (283MB) - L2 fills 128B lines, so partial-row
// gathers over-fetch 4x. Full 256B rows per 32-lane half is sector-optimal.)
__launch_bounds__(256)
__global__ void k_aggregate(const __half* __restrict__ y, const int* __restrict__ offs,
                            const int* __restrict__ bsums, const int2* __restrict__ epack,
                            const float* __restrict__ dinv, const float* __restrict__ bias,
                            __half* __restrict__ out) {
    const int node = __builtin_amdgcn_readfirstlane(blockIdx.x * 4 + (threadIdx.x >> 6));
    const int l = threadIdx.x & 63;
    const int h = l >> 5, j = l & 31;

    int e0 = offs[node] + bsums[node >> 10];
    int e1 = (node + 1 < NN) ? (offs[node + 1] + bsums[(node + 1) >> 10]) : NE;
    e0 = __builtin_amdgcn_readfirstlane(e0);
    e1 = __builtin_amdgcn_readfirstlane(e1);

    const h4v* y4 = (const h4v*)y;               // row stride = 32 (8B units)

    const float di2 = dinv[node] * dinv[node];
    h4v sv = y4[(size_t)node * 32 + j];
    float4 bv = *(const float4*)&bias[4 * j];

    f32x4 acc0 = (f32x4)0.f, acc1 = (f32x4)0.f, acc2 = (f32x4)0.f, acc3 = (f32x4)0.f;

    for (int e = e0; e < e1; e += 8) {
        const int eb = e + 4 * h;
        const int2* pe = epack + eb;
        int2 p0 = pe[0];                          // contiguous 32B per half
        int2 p1 = pe[1];
        int2 p2 = pe[2];
        int2 p3 = pe[3];
        float w0 = (eb + 0 < e1) ? __int_as_float(p0.y) : 0.f;
        float w1 = (eb + 1 < e1) ? __int_as_float(p1.y) : 0.f;
        float w2 = (eb + 2 < e1) ? __int_as_float(p2.y) : 0.f;
        float w3 = (eb + 3 < e1) ? __int_as_float(p3.y) : 0.f;
        h4v v0 = y4[(size_t)p0.x * 32 + j];      // 2 full rows per gather instr
        h4v v1 = y4[(size_t)p1.x * 32 + j];
        h4v v2 = y4[(size_t)p2.x * 32 + j];
        h4v v3 = y4[(size_t)p3.x * 32 + j];
        acc0[0] = fmaf((float)v0[0], w0, acc0[0]); acc0[1] = fmaf((float)v0[1], w0, acc0[1]);
        acc0[2] = fmaf((float)v0[2], w0, acc0[2]); acc0[3] = fmaf((float)v0[3], w0, acc0[3]);
        acc1[0] = fmaf((float)v1[0], w1, acc1[0]); acc1[1] = fmaf((float)v1[1], w1, acc1[1]);
        acc1[2] = fmaf((float)v1[2], w1, acc1[2]); acc1[3] = fmaf((float)v1[3], w1, acc1[3]);
        acc2[0] = fmaf((float)v2[0], w2, acc2[0]); acc2[1] = fmaf((float)v2[1], w2, acc2[1]);
        acc2[2] = fmaf((float)v2[2], w2, acc2[2]); acc2[3] = fmaf((float)v2[3], w2, acc2[3]);
        acc3[0] = fmaf((float)v3[0], w3, acc3[0]); acc3[1] = fmaf((float)v3[1], w3, acc3[1]);
        acc3[2] = fmaf((float)v3[2], w3, acc3[2]); acc3[3] = fmaf((float)v3[3], w3, acc3[3]);
    }

    f32x4 s = (acc0 + acc1) + (acc2 + acc3);
    float t0 = s[0] + __shfl_xor(s[0], 32, 64);
    float t1 = s[1] + __shfl_xor(s[1], 32, 64);
    float t2 = s[2] + __shfl_xor(s[2], 32, 64);
    float t3 = s[3] + __shfl_xor(s[3], 32, 64);

    float r0 = fmaf((float)sv[0], di2, t0) + bv.x;
    float r1 = fmaf((float)sv[1], di2, t1) + bv.y;
    float r2 = fmaf((float)sv[2], di2, t2) + bv.z;
    float r3 = fmaf((float)sv[3], di2, t3) + bv.w;
    if (l < 32) {
        __half2 ha = __floats2half2_rn(fmaxf(r0, 0.f), fmaxf(r1, 0.f));
        __half2 hb = __floats2half2_rn(fmaxf(r2, 0.f), fmaxf(r3, 0.f));
        uint2 o; o.x = *(unsigned*)&ha; o.y = *(unsigned*)&hb;
        *(uint2*)(out + (size_t)node * H + 4 * j) = o;
    }
}

// ---------------------------------------------------------------- launch
extern "C" void kernel_launch(void* const* d_in, const int* in_sizes, int n_in,
                              void* d_out, int out_size, void* d_ws, size_t ws_size,
                              hipStream_t stream) {
    const float* user = (const float*)d_in[0];
    const float* prod = (const float*)d_in[1];
    const int*   eidx = (const int*)  d_in[2];
    const int*   edst = eidx + NE;
    const int*   esrc = eidx;
    const float* Wu = (const float*)d_in[3];
    const float* bu = (const float*)d_in[4];
    const float* Wp = (const float*)d_in[5];
    const float* bp = (const float*)d_in[6];
    const float* W1 = (const float*)d_in[7];
    const float* b1 = (const float*)d_in[8];
    const float* W2 = (const float*)d_in[9];
    const float* b2 = (const float*)d_in[10];
    const float* W3 = (const float*)d_in[11];
    const float* b3 = (const float*)d_in[12];
    const float* Wo = (const float*)d_in[13];
    const float* bo = (const float*)d_in[14];
    float* out = (float*)d_out;

    char* ws = (char*)d_ws;
    size_t p = 0;
    auto alloc = [&](size_t bytes) -> void* {
        void* r = ws + p;
        p += (bytes + 255) & ~(size_t)255;
        return r;
    };
    __half* xA   = (__half*)alloc((size_t)NN * H * 2);
    __half* xB   = (__half*)alloc((size_t)NN * H * 2);
    __half* xU   = (__half*)alloc((size_t)NU * 64 * 2);
    __half* xP   = (__half*)alloc((size_t)NP * 128 * 2);
    int*   cnt   = (int*)  alloc((size_t)NN * 4);
    int*   rank  = (int*)  alloc((size_t)NE * 4);
    int*   offs  = (int*)  alloc((size_t)(NN + 1) * 4);
    float* dinv  = (float*)alloc((size_t)NN * 4);
    int2*  epack = (int2*) alloc((size_t)(NE + 8) * 8);
    int*   bsums = (int*)  alloc(128 * 4);
    __half* whU = (__half*)alloc(128 * 64 * 2);
    __half* wlU = (__half*)alloc(128 * 64 * 2);
    __half* whP = (__half*)alloc(128 * 128 * 2);
    __half* wlP = (__half*)alloc(128 * 128 * 2);
    __half* wh1 = (__half*)alloc(128 * 128 * 2);
    __half* wl1 = (__half*)alloc(128 * 128 * 2);
    __half* wh2 = (__half*)alloc(128 * 128 * 2);
    __half* wl2 = (__half*)alloc(128 * 128 * 2);
    __half* wh3 = (__half*)alloc(128 * 128 * 2);
    __half* wl3 = (__half*)alloc(128 * 128 * 2);
    __half* whO = (__half*)alloc(16 * 128 * 2);
    __half* wlO = (__half*)alloc(16 * 128 * 2);

    const int NBLK = (NN + SCAN_CHUNK - 1) / SCAN_CHUNK;   // 98

    // weight prep + cnt zero + epack pad + input fp16 conversion (one launch)
    {
        const int total = 175784 + NU * 16 + NP * 32;      // 2,575,784
        k_prep<<<(total + 255) / 256, 256, 0, stream>>>(
            Wu, Wp, W1, W2, W3, Wo, user, prod,
            whU, wlU, whP, wlP, wh1, wl1, wh2, wl2, wh3, wl3, whO, wlO,
            xU, xP, cnt, epack);
    }

    // graph structure
    k_count<<<(NE + 255) / 256, 256, 0, stream>>>(edst, cnt, rank, NE);
    k_scan1<<<NBLK, SCAN_TPB, 0, stream>>>(cnt, offs, bsums, dinv, NN);
    k_scan2<<<1, 128, 0, stream>>>(bsums, NBLK);
    k_fill <<<(NE + 255) / 256, 256, 0, stream>>>(esrc, edst, offs, bsums, rank, dinv,
                                                  epack, NE);

    // input feature transforms -> xA (fp16), merged into one launch
    {
        constexpr int blkU = (1563 * 2 + 3) / 4;   // 782
        constexpr int blkP = (1563 * 4 + 3) / 4;   // 1563
        k_gemm_inputs<<<blkU + blkP, 256, 0, stream>>>(
            xU, xP, whU, wlU, whP, wlP, bu, bp, xA, blkU);
    }

    // hidden gemms: NT=1563, CSPLIT=2 -> 3126 waves -> 782 blocks
    const int blkG = (1563 * 2 + 3) / 4;   // 782
    const int blkO = (1563 + 3) / 4;       // 391

    // layer 1
    k_gemm_reg<__half, 128, 128, 4, 4, 128, false, false><<<blkG, 256, 0, stream>>>(xA, wh1, wl1, nullptr, xB, NN, 0);
    k_aggregate<<<NN / 4, 256, 0, stream>>>(xB, offs, bsums, epack, dinv, b1, xA);
    // layer 2
    k_gemm_reg<__half, 128, 128, 4, 4, 128, false, false><<<blkG, 256, 0, stream>>>(xA, wh2, wl2, nullptr, xB, NN, 0);
    k_aggregate<<<NN / 4, 256, 0, stream>>>(xB, offs, bsums, epack, dinv, b2, xA);
    // layer 3
    k_gemm_reg<__half, 128, 128, 4, 4, 128, false, false><<<blkG, 256, 0, stream>>>(xA, wh3, wl3, nullptr, xB, NN, 0);
    k_aggregate<<<NN / 4, 256, 0, stream>>>(xB, offs, bsums, epack, dinv, b3, xA);

    // output head [NN,128] @ [128,16] + bo -> fp32 out
    k_gemm_reg<__half, 128, 128, 4, 1, 16, true, true><<<blkO, 256, 0, stream>>>(xA, whO, wlO, bo, out, NN, 0);
}